// Round 8
// baseline (693.968 us; speedup 1.0000x reference)
//
#include <hip/hip_runtime.h>
#include <hip/hip_bf16.h>

typedef _Float16 half_t;
typedef _Float16 half8 __attribute__((ext_vector_type(8)));
typedef _Float16 half4v __attribute__((ext_vector_type(4)));
typedef float floatx4 __attribute__((ext_vector_type(4)));

// direct global->LDS DMA, 16B per lane; lds ptr must be wave-uniform (HW writes base+lane*16)
__device__ inline void gload16(const half_t* g, half_t* l) {
  __builtin_amdgcn_global_load_lds(
      (const __attribute__((address_space(1))) void*)g,
      (__attribute__((address_space(3))) void*)l, 16, 0, 0);
}

// 4-in-1 wtrans for Wq/Wk/Wv/W1 + zeroing of cs/abar (folds 3 dispatches into 1).
// grid (32, 28): y<4 -> Wq (K=128), y in [4,12) -> Wk, y in [12,20) -> Wv (K=256, N=1024),
// y in [20,28) -> W1 (K=2048, N=128; 256 tiles indexed by (y-20)*32+x).
__global__ __launch_bounds__(256) void wtrans4_kernel(
    const float* __restrict__ Wq, half_t* __restrict__ Wqt,
    const float* __restrict__ Wk, half_t* __restrict__ Wkt,
    const float* __restrict__ Wv, half_t* __restrict__ Wvt,
    const float* __restrict__ W1, half_t* __restrict__ W1t,
    float* __restrict__ zbase /* cs..abar, 278528 floats */) {
  // zero cs+abar (runs before fused/abar in stream order; disjoint buffers, no sync needed)
  {
    unsigned gid = (blockIdx.y * 32 + blockIdx.x) * 256 + threadIdx.x;
    for (unsigned idx = gid; idx < 278528u; idx += 229376u) zbase[idx] = 0.0f;
  }
  __shared__ float sm[32][33];
  int y = blockIdx.y;
  const float* W; half_t* Wt; int K, N, k0, n0;
  if (y < 4)       { W = Wq; Wt = Wqt; K = 128;  N = 1024; k0 = y * 32;        n0 = blockIdx.x * 32; }
  else if (y < 12) { W = Wk; Wt = Wkt; K = 256;  N = 1024; k0 = (y - 4) * 32;  n0 = blockIdx.x * 32; }
  else if (y < 20) { W = Wv; Wt = Wvt; K = 256;  N = 1024; k0 = (y - 12) * 32; n0 = blockIdx.x * 32; }
  else {
    int idx = (y - 20) * 32 + blockIdx.x;  // 0..255
    W = W1; Wt = W1t; K = 2048; N = 128;
    n0 = (idx & 3) * 32; k0 = (idx >> 2) * 32;
  }
  int x = threadIdx.x & 31, y0 = threadIdx.x >> 5;
#pragma unroll
  for (int yy = 0; yy < 4; ++yy) {
    int r = y0 + yy * 8;
    sm[r][x] = W[(size_t)(k0 + r) * N + n0 + x];
  }
  __syncthreads();
#pragma unroll
  for (int yy = 0; yy < 4; ++yy) {
    int r = y0 + yy * 8;
    Wt[(size_t)(n0 + r) * K + k0 + x] = (half_t)sm[x][r];
  }
}

// Merged Q/K/V projection: tile 128x128, BK=32, 4 waves 2x2; grid (128,8,3);
// blockIdx.z selects {input, weight^T, bias, output, K}.
__global__ __launch_bounds__(256) void proj_gemm(
    const float* __restrict__ query, const float* __restrict__ key, const float* __restrict__ value,
    const half_t* __restrict__ Wqt, const half_t* __restrict__ Wkt, const half_t* __restrict__ Wvt,
    const float* __restrict__ bq, const float* __restrict__ bk, const float* __restrict__ bv,
    half_t* __restrict__ Tq, half_t* __restrict__ Tk, half_t* __restrict__ Tv) {
  const int z = blockIdx.z;
  const float* Af = z == 0 ? query : (z == 1 ? key : value);
  const half_t* Bt = z == 0 ? Wqt : (z == 1 ? Wkt : Wvt);
  const float* bias = z == 0 ? bq : (z == 1 ? bk : bv);
  half_t* C = z == 0 ? Tq : (z == 1 ? Tk : Tv);
  const int K = z == 0 ? 128 : 256;

  __shared__ half_t sA[128 * 32];
  __shared__ half_t sB[128 * 32];
  const int t = threadIdx.x;
  const int m0 = blockIdx.x * 128;
  const int n0 = blockIdx.y * 128;
  const int w = t >> 6, lane = t & 63;
  const int wm = w & 1, wn = w >> 1;
  const int lr = lane & 15, lk = lane >> 4;
  const int srow = t >> 2, sg = t & 3;

  floatx4 acc[4][4] = {};

  for (int k0 = 0; k0 < K; k0 += 32) {
    __syncthreads();
#pragma unroll
    for (int rep = 0; rep < 2; ++rep) {
      int row = srow + rep * 64;
      int goff = (sg ^ ((row >> 1) & 3)) * 8;
      const float* p = Af + (size_t)(m0 + row) * K + k0 + sg * 8;
      float4 f0 = *(const float4*)p;
      float4 f1 = *(const float4*)(p + 4);
      half8 hv;
      hv[0] = (half_t)f0.x; hv[1] = (half_t)f0.y;
      hv[2] = (half_t)f0.z; hv[3] = (half_t)f0.w;
      hv[4] = (half_t)f1.x; hv[5] = (half_t)f1.y;
      hv[6] = (half_t)f1.z; hv[7] = (half_t)f1.w;
      *(half8*)&sA[row * 32 + goff] = hv;
      const half_t* q = Bt + (size_t)(n0 + row) * K + k0 + sg * 8;
      *(half8*)&sB[row * 32 + goff] = *(const half8*)q;
    }
    __syncthreads();
    half8 af[4], bf[4];
#pragma unroll
    for (int mt = 0; mt < 4; ++mt) {
      int row = wm * 64 + mt * 16 + lr;
      af[mt] = *(const half8*)&sA[row * 32 + ((lk ^ ((row >> 1) & 3)) * 8)];
    }
#pragma unroll
    for (int nt = 0; nt < 4; ++nt) {
      int row = wn * 64 + nt * 16 + lr;
      bf[nt] = *(const half8*)&sB[row * 32 + ((lk ^ ((row >> 1) & 3)) * 8)];
    }
#pragma unroll
    for (int mt = 0; mt < 4; ++mt)
#pragma unroll
      for (int nt = 0; nt < 4; ++nt)
        acc[mt][nt] = __builtin_amdgcn_mfma_f32_16x16x32_f16(bf[nt], af[mt], acc[mt][nt], 0, 0, 0);
  }

#pragma unroll
  for (int mt = 0; mt < 4; ++mt) {
    int m = m0 + wm * 64 + mt * 16 + lr;
#pragma unroll
    for (int nt = 0; nt < 4; ++nt) {
      int nb = n0 + wn * 64 + nt * 16 + lk * 4;
      floatx4 a = acc[mt][nt];
      float4 bvv = *(const float4*)&bias[nb];
      half4v h;
      h[0] = (half_t)(a[0] + bvv.x); h[1] = (half_t)(a[1] + bvv.y);
      h[2] = (half_t)(a[2] + bvv.z); h[3] = (half_t)(a[3] + bvv.w);
      *(half4v*)&C[(size_t)m * 1024 + nb] = h;
    }
  }
}

// ---------------- FUSED scores GEMM + softmax + column sums ----------------
// grid 2048 wgs (as (32,64)), 256 thr = 4 waves. R5 pipeline kept (global_load_lds staging,
// triple-buffered sK, counted vmcnt(4) + raw s_barrier). R7 counters: FETCH 150 MB (vs 66
// ideal) and WRITE 466 MB (vs 268+1 ideal) -- z's 32 blocks spread over all 8 XCDs, so Tk_z
// was fetched by up to 8 L2s AND the cs atomic lines bounced between XCDs (writeback storm).
// R8 fix: XCD-aware bijective remap -- all 32 q-blocks of a z run on ONE XCD (robust to any
// rotation of the round-robin wg->XCD map). Tk_z fetched once chip-wide; cs atomics L2-local.
__global__ __launch_bounds__(256, 2) void fused_attn_kernel(
    const half_t* __restrict__ Tq, const half_t* __restrict__ Tk,
    float* __restrict__ attn, float* __restrict__ cs) {
  const int wgid = blockIdx.y * 32 + blockIdx.x;
  const int xcd = wgid & 7;
  const int i6 = wgid >> 3;          // 0..255
  const int z = xcd * 8 + (i6 >> 5); // 8 z-slices per XCD
  const int q0 = (i6 & 31) * 32;
  const int t = threadIdx.x;
  const int w = t >> 6, lane = t & 63;
  const int lr = lane & 15, lk = lane >> 4;

  __shared__ half_t sQ[32 * 256];     // linear; XOR-swizzled content (j8 ^= row&7), no pad
  __shared__ half_t sK[3][256 * 32];  // triple-buffered Tk chunks, XOR-swizzle content
  __shared__ float sRS[4][32];

  const half_t* Tqz = Tq + (size_t)z * 262144 + (size_t)q0 * 256;
  const half_t* Tkz = Tk + (size_t)z * 262144;

  // ---- prologue: issue sQ + S(0) + S(1) via global_load_lds ----
#pragma unroll
  for (int r = 0; r < 4; ++r) {
    int i = r * 256 + w * 64 + lane;
    int row = i >> 5, j8 = i & 31;
    gload16(Tqz + (size_t)row * 256 + ((j8 ^ (row & 7)) * 8), &sQ[(r * 256 + w * 64) * 8]);
  }
#pragma unroll
  for (int sp = 0; sp < 2; ++sp) {
#pragma unroll
    for (int r = 0; r < 4; ++r) {
      int i = r * 256 + w * 64 + lane;
      int sl = i >> 2, kg = i & 3;
      int grow = ((sl >> 6) << 8) + (sl & 63);  // g=0 for sp<8
      gload16(Tkz + (size_t)grow * 256 + sp * 32 + ((kg ^ ((sl >> 1) & 3)) * 8),
              &sK[sp][(r * 256 + w * 64) * 8]);
    }
  }

  floatx4 acc[2][16] = {};
#pragma unroll
  for (int s = 0; s < 32; ++s) {
    if (s < 31) {
      asm volatile("s_waitcnt vmcnt(4)" ::: "memory");
    } else {
      asm volatile("s_waitcnt vmcnt(0)" ::: "memory");
    }
    __builtin_amdgcn_sched_barrier(0);
    __builtin_amdgcn_s_barrier();

    if (s + 2 < 32) {
      const int sp = s + 2, g2 = sp >> 3, ks2 = sp & 7;
      half_t* base = &sK[sp % 3][0];
#pragma unroll
      for (int r = 0; r < 4; ++r) {
        int i = r * 256 + w * 64 + lane;
        int sl = i >> 2, kg = i & 3;
        int grow = ((sl >> 6) << 8) + g2 * 64 + (sl & 63);
        gload16(Tkz + (size_t)grow * 256 + ks2 * 32 + ((kg ^ ((sl >> 1) & 3)) * 8),
                base + (r * 256 + w * 64) * 8);
      }
    }

    const int g = s >> 3, ks = s & 7;
    const half_t* kb = &sK[s % 3][0];
    const int j8 = ((ks * 4 + lk) ^ (lr & 7)) * 8;
    half8 af0 = *(const half8*)&sQ[lr * 256 + j8];
    half8 af1 = *(const half8*)&sQ[(16 + lr) * 256 + j8];
#pragma unroll
    for (int l = 0; l < 4; ++l) {
      int sl = w * 64 + l * 16 + lr;
      half8 bf = *(const half8*)&kb[sl * 32 + ((lk ^ ((sl >> 1) & 3)) * 8)];
      acc[0][g * 4 + l] = __builtin_amdgcn_mfma_f32_16x16x32_f16(bf, af0, acc[0][g * 4 + l], 0, 0, 0);
      acc[1][g * 4 + l] = __builtin_amdgcn_mfma_f32_16x16x32_f16(bf, af1, acc[1][g * 4 + l], 0, 0, 0);
    }
  }

  // exp (reference softmax has NO max-subtraction) + per-lane partial row sums
  float rs0 = 0.0f, rs1 = 0.0f;
#pragma unroll
  for (int nt = 0; nt < 16; ++nt) {
#pragma unroll
    for (int j = 0; j < 4; ++j) {
      float v0 = __expf(acc[0][nt][j]);
      float v1 = __expf(acc[1][nt][j]);
      acc[0][nt][j] = v0; acc[1][nt][j] = v1;
      rs0 += v0; rs1 += v1;
    }
  }
  rs0 += __shfl_xor(rs0, 16); rs0 += __shfl_xor(rs0, 32);
  rs1 += __shfl_xor(rs1, 16); rs1 += __shfl_xor(rs1, 32);
  if (lane < 16) { sRS[w][lane] = rs0; sRS[w][16 + lane] = rs1; }
  __syncthreads();
  float inv0 = 1.0f / (sRS[0][lr] + sRS[1][lr] + sRS[2][lr] + sRS[3][lr]);
  float inv1 = 1.0f / (sRS[0][16 + lr] + sRS[1][16 + lr] + sRS[2][16 + lr] + sRS[3][16 + lr]);

  const int nb = w * 256;
  float* attnz = attn + (size_t)z * 1048576;
  float* csz = cs + (size_t)z * 4096;
#pragma unroll
  for (int nt = 0; nt < 16; ++nt) {
    int n = nb + nt * 16 + lk * 4;
    floatx4 o0, o1;
    o0[0] = acc[0][nt][0] * inv0; o0[1] = acc[0][nt][1] * inv0;
    o0[2] = acc[0][nt][2] * inv0; o0[3] = acc[0][nt][3] * inv0;
    o1[0] = acc[1][nt][0] * inv1; o1[1] = acc[1][nt][1] * inv1;
    o1[2] = acc[1][nt][2] * inv1; o1[3] = acc[1][nt][3] * inv1;
    // nontemporal: attn is write-once, never re-read -> keep it out of L2
    __builtin_nontemporal_store(o0, (floatx4*)&attnz[(size_t)(q0 + lr) * 1024 + n]);
    __builtin_nontemporal_store(o1, (floatx4*)&attnz[(size_t)(q0 + 16 + lr) * 1024 + n]);
    float c0 = o0[0] + o1[0], c1 = o0[1] + o1[1], c2 = o0[2] + o1[2], c3 = o0[3] + o1[3];
    c0 += __shfl_xor(c0, 4); c0 += __shfl_xor(c0, 8);
    c1 += __shfl_xor(c1, 4); c1 += __shfl_xor(c1, 8);
    c2 += __shfl_xor(c2, 4); c2 += __shfl_xor(c2, 8);
    c3 += __shfl_xor(c3, 4); c3 += __shfl_xor(c3, 8);
    if (lr < 4) {
      float* p = csz + (size_t)lr * 1024 + n;
      atomicAdd(p + 0, c0);
      atomicAdd(p + 1, c1);
      atomicAdd(p + 2, c2);
      atomicAdd(p + 3, c3);
    }
  }
}

// ---------------- tail: Wcomb = Wo @ W1 (8 GEMM blocks) + bcomb (block 8) ----------------
__global__ __launch_bounds__(256) void tail_kernel(
    const float* __restrict__ Wo, const half_t* __restrict__ W1t,
    const float* __restrict__ W1, const float* __restrict__ bo,
    const float* __restrict__ b1, half_t* __restrict__ Wcomb,
    float* __restrict__ bcomb) {
  const int t = threadIdx.x;
  if (blockIdx.x == 8) {
    // bcomb[j] = b1[j] + sum_k bo[k] * W1[k][j]
    int j = t & 127, h = t >> 7;
    float acc = 0.0f;
    for (int k = h * 1024; k < h * 1024 + 1024; ++k)
      acc += bo[k] * W1[(size_t)k * 128 + j];
    __shared__ float sm[2][128];
    sm[h][j] = acc;
    __syncthreads();
    if (t < 128) bcomb[t] = sm[0][t] + sm[1][t] + b1[t];
    return;
  }
  // GEMM part: Wcomb[m][n] = sum_k Wo[m][k] * W1t[n][k], M=1024 (8x128), N=128, K=2048
  __shared__ half_t sA[128 * 32];
  __shared__ half_t sB[128 * 32];
  const int m0 = blockIdx.x * 128;
  const int w = t >> 6, lane = t & 63;
  const int wm = w & 1, wn = w >> 1;
  const int lr = lane & 15, lk = lane >> 4;
  const int srow = t >> 2, sg = t & 3;

  floatx4 acc[4][4] = {};

  for (int k0 = 0; k0 < 2048; k0 += 32) {
    __syncthreads();
#pragma unroll
    for (int rep = 0; rep < 2; ++rep) {
      int row = srow + rep * 64;
      int goff = (sg ^ ((row >> 1) & 3)) * 8;
      const float* p = Wo + (size_t)(m0 + row) * 2048 + k0 + sg * 8;
      float4 f0 = *(const float4*)p;
      float4 f1 = *(const float4*)(p + 4);
      half8 hv;
      hv[0] = (half_t)f0.x; hv[1] = (half_t)f0.y;
      hv[2] = (half_t)f0.z; hv[3] = (half_t)f0.w;
      hv[4] = (half_t)f1.x; hv[5] = (half_t)f1.y;
      hv[6] = (half_t)f1.z; hv[7] = (half_t)f1.w;
      *(half8*)&sA[row * 32 + goff] = hv;
      const half_t* q = W1t + (size_t)row * 2048 + k0 + sg * 8;  // n0 = 0, rows 0..127
      *(half8*)&sB[row * 32 + goff] = *(const half8*)q;
    }
    __syncthreads();
    half8 af[4], bf[4];
#pragma unroll
    for (int mt = 0; mt < 4; ++mt) {
      int row = wm * 64 + mt * 16 + lr;
      af[mt] = *(const half8*)&sA[row * 32 + ((lk ^ ((row >> 1) & 3)) * 8)];
    }
#pragma unroll
    for (int nt = 0; nt < 4; ++nt) {
      int row = wn * 64 + nt * 16 + lr;
      bf[nt] = *(const half8*)&sB[row * 32 + ((lk ^ ((row >> 1) & 3)) * 8)];
    }
#pragma unroll
    for (int mt = 0; mt < 4; ++mt)
#pragma unroll
      for (int nt = 0; nt < 4; ++nt)
        acc[mt][nt] = __builtin_amdgcn_mfma_f32_16x16x32_f16(bf[nt], af[mt], acc[mt][nt], 0, 0, 0);
  }

#pragma unroll
  for (int mt = 0; mt < 4; ++mt) {
    int m = m0 + wm * 64 + mt * 16 + lr;
#pragma unroll
    for (int nt = 0; nt < 4; ++nt) {
      int nb = wn * 64 + nt * 16 + lk * 4;
      floatx4 a = acc[mt][nt];
      half4v h;
      h[0] = (half_t)a[0]; h[1] = (half_t)a[1];
      h[2] = (half_t)a[2]; h[3] = (half_t)a[3];
      *(half4v*)&Wcomb[(size_t)m * 128 + nb] = h;
    }
  }
}

// ---------------- abar[b, r*256+d] = (1/1024) sum_{h,k} cs[bh][r][k] * Tv[bh][k][d] ----------------
__global__ __launch_bounds__(256) void abar_kernel(const float* __restrict__ cs,
                                                   const half_t* __restrict__ Tv,
                                                   float* __restrict__ abar) {
  int b = blockIdx.x, r = blockIdx.y, kc = blockIdx.z;
  int d = threadIdx.x;
  __shared__ float scs[4][128];
  for (int idx = d; idx < 512; idx += 256) {
    int h = idx >> 7, k = idx & 127;
    scs[h][k] = cs[(size_t)(b * 4 + h) * 4096 + (size_t)r * 1024 + kc * 128 + k];
  }
  __syncthreads();
  float acc = 0.0f;
  for (int h = 0; h < 4; ++h) {
    const half_t* tv = Tv + (size_t)(b * 4 + h) * 262144 + (size_t)kc * 32768 + d;
#pragma unroll 4
    for (int k = 0; k < 128; ++k)
      acc += scs[h][k] * (float)tv[(size_t)k * 256];
  }
  atomicAdd(&abar[b * 1024 + r * 256 + d], acc * (1.0f / 1024.0f));
}

// ---------------- out[b][j] = bcomb[j] + sum_c abar[b][c] * Wcomb[c][j] ----------------
__global__ __launch_bounds__(256) void final2_kernel(const float* __restrict__ abar,
                                                     const half_t* __restrict__ Wcomb,
                                                     const float* __restrict__ bcomb,
                                                     float* __restrict__ out) {
  int b = blockIdx.x, t = threadIdx.x;
  int j = t & 127, h = t >> 7;
  __shared__ float sa[1024];
  __shared__ float sm[2][128];
  for (int i = t; i < 1024; i += 256) sa[i] = abar[(size_t)b * 1024 + i];
  __syncthreads();
  float acc = 0.0f;
  for (int c = h * 512; c < h * 512 + 512; ++c)
    acc += sa[c] * (float)Wcomb[(size_t)c * 128 + j];
  sm[h][j] = acc;
  __syncthreads();
  if (t < 128) out[(size_t)b * 128 + t] = sm[0][t] + sm[1][t] + bcomb[t];
}

extern "C" void kernel_launch(void* const* d_in, const int* in_sizes, int n_in,
                              void* d_out, int out_size, void* d_ws, size_t ws_size,
                              hipStream_t stream) {
  const float* query = (const float*)d_in[0];
  const float* key   = (const float*)d_in[1];
  const float* value = (const float*)d_in[2];
  const float* Wq = (const float*)d_in[3];
  const float* bq = (const float*)d_in[4];
  const float* Wk = (const float*)d_in[5];
  const float* bk = (const float*)d_in[6];
  const float* Wv = (const float*)d_in[7];
  const float* bv = (const float*)d_in[8];
  const float* Wo = (const float*)d_in[9];
  const float* bo = (const float*)d_in[10];
  const float* W1 = (const float*)d_in[11];
  const float* b1 = (const float*)d_in[12];

  // workspace layout (bytes) -- W1t/Wcomb/bcomb moved PAST Wvt (no longer overlap Tq, since
  // wtrans4 now writes W1t before proj_gemm writes Tq; d_ws is ~1 GiB per the poison fill)
  char* ws = (char*)d_ws;
  half_t* Tq   = (half_t*)(ws + 0);          // 16M halves  [b][s][1024]
  half_t* Tk   = (half_t*)(ws + 33554432);   // 16M halves
  half_t* Tv   = (half_t*)(ws + 67108864);   // 16M halves  (live until abar)
  float*  cs   = (float*)(ws + 100663296);   // [64][4][1024] f32  (zeroed by wtrans4)
  float*  abar = (float*)(ws + 101711872);   // [16][1024] f32     (zeroed by wtrans4)
  half_t* Wqt  = (half_t*)(ws + 101777408);  // [1024][128] f16
  half_t* Wkt  = (half_t*)(ws + 102039552);  // [1024][256] f16
  half_t* Wvt  = (half_t*)(ws + 102563840);  // [1024][256] f16
  half_t* W1t  = (half_t*)(ws + 103088128);  // [128][2048] f16
  half_t* Wcomb = (half_t*)(ws + 103612416); // [1024][128] f16
  float*  bcomb = (float*)(ws + 103874560);  // [128] f32

  float* out  = (float*)d_out;
  float* attn = out + 2048;  // [64][1024][1024] f32

  // 1. weight transposes (Wq/Wk/Wv/W1) + zero cs/abar
  wtrans4_kernel<<<dim3(32, 28), 256, 0, stream>>>(Wq, Wqt, Wk, Wkt, Wv, Wvt, W1, W1t, cs);

  // 2. merged Q/K/V projections
  proj_gemm<<<dim3(128, 8, 3), 256, 0, stream>>>(query, key, value, Wqt, Wkt, Wvt,
                                                 bq, bk, bv, Tq, Tk, Tv);

  // 3. fused scores + softmax + nontemporal attn write + column sums (XCD-local z)
  fused_attn_kernel<<<dim3(32, 64), 256, 0, stream>>>(Tq, Tk, attn, cs);

  // 4. Wcomb = Wo @ W1 + bcomb = bo @ W1 + b1 (merged)
  tail_kernel<<<9, 256, 0, stream>>>(Wo, W1t, W1, bo, b1, Wcomb, bcomb);

  // 5-6. abar, final output
  abar_kernel<<<dim3(16, 4, 8), 256, 0, stream>>>(cs, Tv, abar);
  final2_kernel<<<16, 256, 0, stream>>>(abar, Wcomb, bcomb, out);
}